// Round 6
// baseline (13374.091 us; speedup 1.0000x reference)
//
#include <hip/hip_runtime.h>
#include <type_traits>

typedef unsigned long long u64;
typedef unsigned int u32;

#define BLOCK     256           // 4 waves
#define WAVES     4
#define TILE      4096
#define SUBT      1024
#define CHUNKS    16            // SUBT/64
#define KSHIFT    21
#define KBIAS     (1LL << 21)   // min key -1,787,119 > -2^21; max < 2^33
#define KMASK     ((1u << 21) - 1)
#define GRP       128
#define VAL30     ((1u << 30) - 1)
#define FLG_AGG   (1u << 30)
#define FLG_PRE   (2u << 30)

// OneSweep pass plan (33 key bits = 8+8+9+8, LSD):
//  p1: u64 r256 @21, A->B        p2: u64 r256 @29, B->A
//  p3: u64 r512 @37, A->B staged/written as u32 = ((k>>46)<<21)|idx
//  p4: u32 r256 @21, B->dout (idx)
// Global hists for all 4 passes computed in keygen; per-tile offsets via
// ticket-ordered decoupled lookback (tstate[s][d][tile], memset per pass).

__device__ __forceinline__ void hash3(long long x, long long y, long long z,
                                      long long boff, long long* v) {
  long long x1 = x >> 4, y1 = y >> 4, z1 = z >> 3;
  long long x2 = x & 15, y2 = y & 15, z2 = z & 7;
  long long sx  = 1 - 2*(x1 & 1), sy  = 1 - 2*(y1 & 1), sz  = 1 - 2*(z1 & 1);
  long long s2x = 1 - 2*(x2 & 1), s2y = 1 - 2*(y2 & 1), s2z = 1 - 2*(z2 & 1);
  v[0] = (99*y1 + 9801*z1 + sy*x1)*55296 + sy*(48*x2 + 2304*z2 + s2x*y2) + boff;
  v[1] = (99*z1 + 2673*x1 + sz*y1)*55296 + sz*(24*y2 + 1152*x2 + s2y*z2) + boff;
  v[2] = (27*x1 + 2673*y1 + sx*z1)*55296 + sx*(48*z2 + 1152*y2 + s2z*x2) + boff;
}

__global__ void count_k(const int* __restrict__ coords, unsigned* __restrict__ counts, int N) {
  __shared__ unsigned c[8];
  if (threadIdx.x < 8) c[threadIdx.x] = 0;
  __syncthreads();
  for (int i = blockIdx.x*blockDim.x + threadIdx.x; i < N; i += gridDim.x*blockDim.x)
    atomicAdd(&c[coords[4*i] & 7], 1u);
  __syncthreads();
  if (threadIdx.x < 8) atomicAdd(&counts[threadIdx.x], c[threadIdx.x]);
}

__global__ void prefix_k(const unsigned* __restrict__ counts, long long* __restrict__ meta,
                         const int* __restrict__ bsz) {
  int NB = *bsz; if (NB > 8) NB = 8;
  long long run_bs = 0, run_bsp = 0;
  meta[0] = 0;
  for (int b = 0; b < NB; b++) {
    long long c  = (long long)counts[b];
    long long cp = (c + GRP - 1) / GRP * GRP;
    long long r  = c % GRP;
    meta[9 + b]  = run_bsp - run_bs;
    meta[17 + b] = r ? (run_bsp + cp - GRP + r) : 0x7fffffffffffffffLL;
    run_bs += c; run_bsp += cp;
    meta[b + 1] = run_bsp;
  }
  meta[25] = run_bsp;
  meta[26] = NB;
}

__global__ void flat2win_k(const long long* __restrict__ meta, int* __restrict__ dout) {
  long long p = (long long)blockIdx.x * blockDim.x + threadIdx.x;
  long long Np = meta[25];
  if (p >= Np) return;
  int NB = (int)meta[26];
  int b = 0;
  while (b < NB - 1 && meta[b + 1] <= p) b++;
  long long pad = (p >= meta[17 + b]) ? 1 : 0;
  dout[p] = (int)(p - GRP * pad - meta[9 + b]);
}

// keygen + GLOBAL histograms for all 4 passes (per sort) + win2flat aux
__global__ void __launch_bounds__(BLOCK) keygen_k(const int* __restrict__ coords,
                                                  u64* __restrict__ keys,
                                                  u32* __restrict__ ghist,
                                                  const long long* __restrict__ meta,
                                                  int* __restrict__ dout,
                                                  int N, int g0, int g, int doAux) {
  __shared__ u32 cnt[6 * 1280];   // per sort: [0,256) p1, [256,512) p2, [512,1024) p3, [1024,1280) p4
  int b = blockIdx.x, tid = threadIdx.x;
  int nb = g * 1280;
  for (int j = tid; j < nb; j += BLOCK) cnt[j] = 0;
  __syncthreads();
  long long Np = meta[25];
  for (int t = 0; t < CHUNKS; t++) {
    int i = b * TILE + t * BLOCK + tid;
    if (i < N) {
      int4 c4 = ((const int4*)coords)[i];
      long long boff = (long long)c4.x * 167772160LL;
      long long v[6];
      hash3(c4.y,     c4.z,     c4.w,     boff, v);
      hash3(c4.y + 8, c4.z + 8, c4.w + 4, boff, v + 3);
      #pragma unroll
      for (int s = 0; s < 6; s++) {
        if (s >= g0 && s < g0 + g) {
          u64 kb = (u64)(v[s] + KBIAS);
          keys[(size_t)(s - g0) * N + i] = (kb << KSHIFT) | (unsigned)i;
          u32* c = &cnt[(s - g0) * 1280];
          atomicAdd(&c[(u32)kb & 255], 1u);
          atomicAdd(&c[256 + (((u32)kb >> 8) & 255)], 1u);
          atomicAdd(&c[512 + ((u32)(kb >> 16) & 511)], 1u);
          atomicAdd(&c[1024 + (u32)(kb >> 25)], 1u);
        }
      }
      if (doAux) dout[Np + i] = (int)(i + meta[9 + c4.x]);
    }
  }
  __syncthreads();
  for (int j = tid; j < nb; j += BLOCK) {
    u32 v = cnt[j];
    if (v) {
      int s = j / 1280, r = j % 1280, p, d;
      if (r < 256)       { p = 0; d = r; }
      else if (r < 512)  { p = 1; d = r - 256; }
      else if (r < 1024) { p = 2; d = r - 512; }
      else               { p = 3; d = r - 1024; }
      atomicAdd(&ghist[((size_t)s * 4 + p) * 512 + d], v);
    }
  }
}

// exclusive scan of each (sort, pass) global histogram -> digit bases
__global__ void __launch_bounds__(64) gscan_k(const u32* __restrict__ ghist,
                                              u32* __restrict__ gbase) {
  int p = blockIdx.x, s = blockIdx.y, lane = threadIdx.x;
  int R = (p == 2) ? 512 : 256;
  const u32* h = ghist + ((size_t)s * 4 + p) * 512;
  u32* o = gbase + ((size_t)s * 4 + p) * 512;
  u32 run = 0;
  for (int c = 0; c < R / 64; c++) {
    u32 v = h[c * 64 + lane], x = v;
    for (int off = 1; off < 64; off <<= 1) { u32 u = __shfl_up(x, off); if (lane >= off) x += u; }
    o[c * 64 + lane] = run + x - v;
    run += __shfl(x, 63);
  }
}

// OneSweep scatter: rank in block, publish aggregate, decoupled lookback for
// per-tile digit offsets, LDS-staged coalesced write-out.
// MODE 0: u64->u64   MODE 1: u64->u32 shrink   MODE 2: u32->int32 dout
template<int RB, int SHIFT, int MODE>
__global__ void __launch_bounds__(BLOCK) scatter_os(const void* __restrict__ srcv,
                                                    void* __restrict__ dstv,
                                                    const u32* __restrict__ gbase,
                                                    u32* __restrict__ tstate,
                                                    int* __restrict__ ticket,
                                                    int N, int B, int pass,
                                                    int* __restrict__ dout,
                                                    const long long* __restrict__ meta, int g0) {
  constexpr int RADIXN = 1 << RB;
  constexpr int DPT = (RADIXN + BLOCK - 1) / BLOCK;
  using KT = typename std::conditional<MODE == 2, u32, u64>::type;   // source type
  using ST = typename std::conditional<MODE == 0, u64, u32>::type;   // staged type
  __shared__ ST items[TILE];
  __shared__ unsigned short dig[MODE == 1 ? TILE : 64];
  __shared__ unsigned short cnt[WAVES][RADIXN];
  __shared__ u32 tot[RADIXN];
  __shared__ u32 glb[RADIXN];
  __shared__ int exl[RADIXN];
  __shared__ int fix[RADIXN];
  __shared__ int vt_s;
  int tid = threadIdx.x, wave = tid >> 6, lane = tid & 63;
  if (tid == 0) vt_s = atomicAdd(ticket, 1);     // ticket order => lookback progress
  for (int j = tid; j < WAVES * RADIXN; j += BLOCK) ((unsigned short*)cnt)[j] = 0;
  __syncthreads();
  int vt = vt_s, s = vt / B, b = vt % B;

  const KT* in = (const KT*)srcv + (size_t)s * N;
  int subbase = b * TILE + wave * SUBT;
  bool full = (subbase + SUBT <= N);
  KT k[CHUNKS]; u32 pd[CHUNKS];
  if (full) {
    #pragma unroll
    for (int t = 0; t < CHUNKS; t++) k[t] = in[subbase + t * 64 + lane];
    #pragma unroll
    for (int t = 0; t < CHUNKS; t++) {
      unsigned d = (unsigned)(k[t] >> SHIFT) & (RADIXN - 1);
      u64 m = ~0ull;
      #pragma unroll
      for (int bit = 0; bit < RB; bit++) {
        u64 bal = __ballot((d >> bit) & 1);
        m &= ((d >> bit) & 1) ? bal : ~bal;
      }
      unsigned rank = __builtin_amdgcn_mbcnt_hi((u32)(m >> 32),
                        __builtin_amdgcn_mbcnt_lo((u32)m, 0u));
      unsigned pbase = cnt[wave][d];             // lockstep: all read before leader writes
      pd[t] = d | ((pbase + rank) << RB);
      if (rank == 0) cnt[wave][d] = (unsigned short)(pbase + (unsigned)__popcll(m));
    }
  } else {
    #pragma unroll
    for (int t = 0; t < CHUNKS; t++) k[t] = in[min(subbase + t * 64 + lane, N - 1)];
    #pragma unroll
    for (int t = 0; t < CHUNKS; t++) {
      int i = subbase + t * 64 + lane;
      bool valid = i < N;
      unsigned d = (unsigned)(k[t] >> SHIFT) & (RADIXN - 1);
      u64 m = __ballot(valid);
      #pragma unroll
      for (int bit = 0; bit < RB; bit++) {
        u64 bal = __ballot(valid && ((d >> bit) & 1));
        m &= ((d >> bit) & 1) ? bal : ~bal;
      }
      unsigned rank = __builtin_amdgcn_mbcnt_hi((u32)(m >> 32),
                        __builtin_amdgcn_mbcnt_lo((u32)m, 0u));
      unsigned pbase = cnt[wave][d];
      pd[t] = d | ((pbase + rank) << RB);
      if (valid && rank == 0) cnt[wave][d] = (unsigned short)(pbase + (unsigned)__popcll(m));
    }
  }
  __syncthreads();

  // totals; publish aggregate FIRST, then lookback, then publish inclusive
  u32 sc[DPT][3];
  #pragma unroll
  for (int q = 0; q < DPT; q++) {
    int d = q * BLOCK + tid;
    u32 a0 = cnt[0][d], a1 = cnt[1][d], a2 = cnt[2][d], a3 = cnt[3][d];
    sc[q][0] = a0; sc[q][1] = a1; sc[q][2] = a2;
    u32 t_ = a0 + a1 + a2 + a3;
    tot[d] = t_;
    size_t row = ((size_t)s * RADIXN + d) * (size_t)B;
    if (b == 0) {
      glb[d] = 0;
      __hip_atomic_store(&tstate[row], FLG_PRE | t_, __ATOMIC_RELEASE, __HIP_MEMORY_SCOPE_AGENT);
    } else {
      __hip_atomic_store(&tstate[row + b], FLG_AGG | t_, __ATOMIC_RELEASE, __HIP_MEMORY_SCOPE_AGENT);
      u32 run = 0; int t = b - 1;
      while (true) {
        u32 st = __hip_atomic_load(&tstate[row + t], __ATOMIC_ACQUIRE, __HIP_MEMORY_SCOPE_AGENT);
        if (!(st >> 30)) { __builtin_amdgcn_s_sleep(1); continue; }
        run += st & VAL30;
        if (st & FLG_PRE) break;
        t--;
      }
      glb[d] = run;
      __hip_atomic_store(&tstate[row + b], FLG_PRE | (run + t_), __ATOMIC_RELEASE, __HIP_MEMORY_SCOPE_AGENT);
    }
  }
  __syncthreads();
  if (tid < 64) {                                 // wave0: exclusive scan of tile totals
    u32 run = 0;
    #pragma unroll
    for (int c = 0; c < RADIXN / 64; c++) {
      int dd = c * 64 + tid;
      u32 v = tot[dd], x = v;
      for (int off = 1; off < 64; off <<= 1) { u32 u = __shfl_up(x, off); if (tid >= off) x += u; }
      exl[dd] = (int)(run + x - v);
      run += __shfl(x, 63);
    }
  }
  __syncthreads();
  const u32* grow = gbase + ((size_t)s * 4 + pass) * 512;
  #pragma unroll
  for (int q = 0; q < DPT; q++) {
    int d = q * BLOCK + tid;
    int e = exl[d];
    cnt[0][d] = (unsigned short)e;
    cnt[1][d] = (unsigned short)(e + sc[q][0]);
    cnt[2][d] = (unsigned short)(e + sc[q][0] + sc[q][1]);
    cnt[3][d] = (unsigned short)(e + sc[q][0] + sc[q][1] + sc[q][2]);
    fix[d] = (int)(grow[d] + glb[d]) - e;         // global = fix[d] + local slot
  }
  __syncthreads();

  #pragma unroll
  for (int t = 0; t < CHUNKS; t++) {
    int i = subbase + t * 64 + lane;
    if (i < N) {
      unsigned d = pd[t] & (RADIXN - 1);
      unsigned lr = pd[t] >> RB;
      unsigned pos = (unsigned)cnt[wave][d] + lr;
      if constexpr (MODE == 1) {
        items[pos] = (u32)(((k[t] >> 46) << 21) | ((u32)k[t] & KMASK));
        dig[pos] = (unsigned short)d;
      } else {
        items[pos] = (ST)k[t];
      }
    }
  }
  __syncthreads();

  int validCount = N - b * TILE; if (validCount > TILE) validCount = TILE;
  long long obase = 0;
  if (MODE == 2) obase = meta[25] + (long long)N * (1 + g0 + s);
  u64* out64 = (u64*)dstv + (size_t)s * N;
  u32* out32 = (u32*)dstv + (size_t)s * N;
  #pragma unroll 4
  for (int t = 0; t < CHUNKS; t++) {
    int j = t * BLOCK + tid;
    if (j < validCount) {
      ST kk = items[j];
      if constexpr (MODE == 0) {
        unsigned d = (unsigned)(kk >> SHIFT) & (RADIXN - 1);
        out64[fix[d] + j] = kk;
      } else if constexpr (MODE == 1) {
        unsigned d = dig[j];
        out32[fix[d] + j] = kk;
      } else {
        unsigned d = (unsigned)(kk >> SHIFT) & (RADIXN - 1);
        dout[obase + fix[d] + j] = (int)(kk & KMASK);
      }
    }
  }
}

extern "C" void kernel_launch(void* const* d_in, const int* in_sizes, int n_in,
                              void* d_out, int out_size, void* d_ws, size_t ws_size,
                              hipStream_t stream) {
  const int* coords = (const int*)d_in[0];
  const int* bsz    = (const int*)d_in[1];
  int N = in_sizes[0] / 4;
  int* dout = (int*)d_out;
  char* ws = (char*)d_ws;
  int B = (N + TILE - 1) / TILE;

  auto align256 = [](size_t x) { return (x + 255) & ~(size_t)255; };

  int g = 1;
  size_t offGH = 512, offGB = 0, offTk = 0, offTS = 0, tsz = 0, offA = 0, offB = 0;
  const int cands[4] = {6, 3, 2, 1};
  for (int ci = 0; ci < 4; ci++) {
    int cg = cands[ci];
    size_t oGB = offGH + (size_t)cg * 8192;        // ghist: cg*4*512*4
    size_t oTk = align256(oGB + (size_t)cg * 8192); // gbase
    size_t oTS = oTk + 256;
    size_t ts  = (size_t)cg * 512 * B * 4;
    size_t oA  = align256(oTS + ts);
    size_t oB  = oA + (size_t)cg * N * 8;
    size_t need = oB + (size_t)cg * N * 8;
    if (need <= ws_size || cg == 1) {
      g = cg; offGB = oGB; offTk = oTk; offTS = oTS; tsz = ts; offA = oA; offB = oB;
      if (need <= ws_size) break;
    }
  }

  unsigned*  counts = (unsigned*)ws;
  long long* meta   = (long long*)(ws + 64);
  u32*       ghist  = (u32*)(ws + offGH);
  u32*       gbase  = (u32*)(ws + offGB);
  int*       ticket = (int*)(ws + offTk);
  u32*       tstate = (u32*)(ws + offTS);
  u64*       keysA  = (u64*)(ws + offA);
  u64*       keysB  = (u64*)(ws + offB);

  hipMemsetAsync(ws, 0, 512, stream);
  count_k<<<1024, 256, 0, stream>>>(coords, counts, N);
  prefix_k<<<1, 1, 0, stream>>>(counts, meta, bsz);
  flat2win_k<<<(N + 8 * GRP + 255) / 256, 256, 0, stream>>>(meta, dout);

  for (int g0 = 0; g0 < 6; g0 += g) {
    hipMemsetAsync(ghist, 0, (size_t)g * 8192, stream);
    keygen_k<<<B, BLOCK, 0, stream>>>(coords, keysA, ghist, meta, dout, N, g0, g, g0 == 0);
    gscan_k<<<dim3(4, g), 64, 0, stream>>>(ghist, gbase);

    // p1: u64 r256 @21, A -> B
    hipMemsetAsync(ws + offTk, 0, 256 + tsz, stream);
    scatter_os<8, 21, 0><<<B * g, BLOCK, 0, stream>>>(keysA, keysB, gbase, tstate, ticket,
                                                      N, B, 0, dout, meta, g0);
    // p2: u64 r256 @29, B -> A
    hipMemsetAsync(ws + offTk, 0, 256 + tsz, stream);
    scatter_os<8, 29, 0><<<B * g, BLOCK, 0, stream>>>(keysB, keysA, gbase, tstate, ticket,
                                                      N, B, 1, dout, meta, g0);
    // p3: u64 r512 @37, A -> B (shrink to u32)
    hipMemsetAsync(ws + offTk, 0, 256 + tsz, stream);
    scatter_os<9, 37, 1><<<B * g, BLOCK, 0, stream>>>(keysA, keysB, gbase, tstate, ticket,
                                                      N, B, 2, dout, meta, g0);
    // p4: u32 r256 @21, B -> dout
    hipMemsetAsync(ws + offTk, 0, 256 + tsz, stream);
    scatter_os<8, 21, 2><<<B * g, BLOCK, 0, stream>>>(keysB, keysA, gbase, tstate, ticket,
                                                      N, B, 3, dout, meta, g0);
  }
}

// Round 7
// 472.471 us; speedup vs baseline: 28.3067x; 28.3067x over previous
//
#include <hip/hip_runtime.h>
#include <type_traits>

typedef unsigned long long u64;
typedef unsigned int u32;

#define BLOCK     256           // 4 waves
#define WAVES     4
#define TILE      4096          // items per hist/scatter block
#define SUBT      1024          // items per wave (contiguous, stability)
#define CHUNKS    16            // SUBT/64
#define KSHIFT    21
#define KBIAS     (1LL << 21)   // min key -1,787,119 > -2^21; max < 2^33
#define KMASK     ((1u << 21) - 1)
#define GRP       128

// Pass plan (33 key bits = 8+8+9+8, LSD)  [R4 split — best measured]:
//  p1: u64, radix 256, shift 21  (key bits [0,8))   hist fused into keygen
//  p2: u64, radix 256, shift 29  (key bits [8,16))
//  p3: u64 -> u32, radix 512, shift 37 (key bits [16,25)); out = ((k>>46)<<21)|idx
//  p4: u32, radix 256, shift 21  (key bits [25,33)) -> int32 dout

__device__ __forceinline__ void hash3(long long x, long long y, long long z,
                                      long long boff, long long* v) {
  long long x1 = x >> 4, y1 = y >> 4, z1 = z >> 3;
  long long x2 = x & 15, y2 = y & 15, z2 = z & 7;
  long long sx  = 1 - 2*(x1 & 1), sy  = 1 - 2*(y1 & 1), sz  = 1 - 2*(z1 & 1);
  long long s2x = 1 - 2*(x2 & 1), s2y = 1 - 2*(y2 & 1), s2z = 1 - 2*(z2 & 1);
  v[0] = (99*y1 + 9801*z1 + sy*x1)*55296 + sy*(48*x2 + 2304*z2 + s2x*y2) + boff;
  v[1] = (99*z1 + 2673*x1 + sz*y1)*55296 + sz*(24*y2 + 1152*x2 + s2y*z2) + boff;
  v[2] = (27*x1 + 2673*y1 + sx*z1)*55296 + sx*(48*z2 + 1152*y2 + s2z*x2) + boff;
}

__global__ void count_k(const int* __restrict__ coords, unsigned* __restrict__ counts, int N) {
  __shared__ unsigned c[8];
  if (threadIdx.x < 8) c[threadIdx.x] = 0;
  __syncthreads();
  for (int i = blockIdx.x*blockDim.x + threadIdx.x; i < N; i += gridDim.x*blockDim.x)
    atomicAdd(&c[coords[4*i] & 7], 1u);
  __syncthreads();
  if (threadIdx.x < 8) atomicAdd(&counts[threadIdx.x], c[threadIdx.x]);
}

__global__ void prefix_k(const unsigned* __restrict__ counts, long long* __restrict__ meta,
                         const int* __restrict__ bsz) {
  int NB = *bsz; if (NB > 8) NB = 8;
  long long run_bs = 0, run_bsp = 0;
  meta[0] = 0;
  for (int b = 0; b < NB; b++) {
    long long c  = (long long)counts[b];
    long long cp = (c + GRP - 1) / GRP * GRP;
    long long r  = c % GRP;
    meta[9 + b]  = run_bsp - run_bs;
    meta[17 + b] = r ? (run_bsp + cp - GRP + r) : 0x7fffffffffffffffLL;
    run_bs += c; run_bsp += cp;
    meta[b + 1] = run_bsp;
  }
  meta[25] = run_bsp;
  meta[26] = NB;
}

__global__ void flat2win_k(const long long* __restrict__ meta, int* __restrict__ dout) {
  long long p = (long long)blockIdx.x * blockDim.x + threadIdx.x;
  long long Np = meta[25];
  if (p >= Np) return;
  int NB = (int)meta[26];
  int b = 0;
  while (b < NB - 1 && meta[b + 1] <= p) b++;
  long long pad = (p >= meta[17 + b]) ? 1 : 0;
  dout[p] = (int)(p - GRP * pad - meta[9 + b]);
}

// fused keygen + pass-1 per-block histogram (radix 256 of low 8 key bits) + win2flat aux
__global__ void __launch_bounds__(BLOCK) keygen_k(const int* __restrict__ coords,
                                                  u64* __restrict__ keys,
                                                  u32* __restrict__ hist,
                                                  const long long* __restrict__ meta,
                                                  int* __restrict__ dout,
                                                  int N, int B, int g0, int g, int doAux) {
  __shared__ u32 cnt[6 * 256];
  int b = blockIdx.x, tid = threadIdx.x;
  int nb = g * 256;
  for (int j = tid; j < nb; j += BLOCK) cnt[j] = 0;
  __syncthreads();
  long long Np = meta[25];
  for (int t = 0; t < CHUNKS; t++) {
    int i = b * TILE + t * BLOCK + tid;
    if (i < N) {
      int4 c4 = ((const int4*)coords)[i];
      long long boff = (long long)c4.x * 167772160LL;
      long long v[6];
      hash3(c4.y,     c4.z,     c4.w,     boff, v);
      hash3(c4.y + 8, c4.z + 8, c4.w + 4, boff, v + 3);
      #pragma unroll
      for (int s = 0; s < 6; s++) {
        if (s >= g0 && s < g0 + g) {
          u64 kb = (u64)(v[s] + KBIAS);
          keys[(size_t)(s - g0) * N + i] = (kb << KSHIFT) | (unsigned)i;
          atomicAdd(&cnt[(s - g0) * 256 + ((unsigned)kb & 255)], 1u);
        }
      }
      if (doAux) dout[Np + i] = (int)(i + meta[9 + c4.x]);
    }
  }
  __syncthreads();
  for (int j = tid; j < nb; j += BLOCK) {
    int s = j >> 8, d = j & 255;
    hist[((size_t)s * B + b) * 256 + d] = cnt[j];
  }
}

template<typename KT, int RADIXN, int SHIFT>
__global__ void __launch_bounds__(BLOCK) hist_k(const KT* __restrict__ src,
                                                u32* __restrict__ hist, int N, int B) {
  __shared__ u32 cnt[RADIXN];
  int s = blockIdx.y, b = blockIdx.x, tid = threadIdx.x;
  for (int j = tid; j < RADIXN; j += BLOCK) cnt[j] = 0;
  __syncthreads();
  const KT* in = src + (size_t)s * N;
  #pragma unroll 4
  for (int t = 0; t < CHUNKS; t++) {
    int i = b * TILE + t * BLOCK + tid;
    if (i < N) {
      unsigned d = (unsigned)(in[i] >> SHIFT) & (RADIXN - 1);
      atomicAdd(&cnt[d], 1u);
    }
  }
  __syncthreads();
  for (int j = tid; j < RADIXN; j += BLOCK) hist[((size_t)s * B + b) * RADIXN + j] = cnt[j];
}

// per-sort single block: in-place exclusive scan of per-block hists + digit-base scan
template<int RADIXN>
__global__ void __launch_bounds__(BLOCK) scan_k(u32* __restrict__ hist,
                                                u32* __restrict__ dbase, int B) {
  __shared__ u32 tot[RADIXN];
  int s = blockIdx.x, tid = threadIdx.x;
  for (int d = tid; d < RADIXN; d += BLOCK) {
    u32 run = 0; int b = 0;
    for (; b + 8 <= B; b += 8) {
      u32 v[8];
      #pragma unroll
      for (int j = 0; j < 8; j++) v[j] = hist[((size_t)s * B + b + j) * RADIXN + d];
      #pragma unroll
      for (int j = 0; j < 8; j++) { hist[((size_t)s * B + b + j) * RADIXN + d] = run; run += v[j]; }
    }
    for (; b < B; b++) {
      size_t x = ((size_t)s * B + b) * RADIXN + d;
      u32 v = hist[x]; hist[x] = run; run += v;
    }
    tot[d] = run;
  }
  __syncthreads();
  if (tid < 64) {
    u32 run = 0;
    #pragma unroll
    for (int c = 0; c < (RADIXN + 63) / 64; c++) {
      int dd = c * 64 + tid;
      u32 v = (dd < RADIXN) ? tot[dd] : 0, x = v;
      for (int off = 1; off < 64; off <<= 1) { u32 u = __shfl_up(x, off); if (tid >= off) x += u; }
      if (dd < RADIXN) dbase[(size_t)s * 512 + dd] = run + x - v;
      run += __shfl(x, 63);
    }
  }
}

// register-stash scatter; u16 per-wave counters; mbcnt rank; full-tile fast path.
// MODE 0: u64->u64   MODE 1: u64->u32 shrink (stages u32+dig)   MODE 2: u32->int32 dout
template<int RB, int SHIFT, int MODE>
__global__ void __launch_bounds__(BLOCK) scatter_k(const void* __restrict__ srcv,
                                                   void* __restrict__ dstv,
                                                   const u32* __restrict__ hist,
                                                   const u32* __restrict__ dbase,
                                                   int N, int B,
                                                   int* __restrict__ dout,
                                                   const long long* __restrict__ meta, int g0) {
  constexpr int RADIXN = 1 << RB;
  constexpr int DPT = (RADIXN + BLOCK - 1) / BLOCK;
  using KT = typename std::conditional<MODE == 2, u32, u64>::type;   // source type
  using ST = typename std::conditional<MODE == 0, u64, u32>::type;   // staged type
  __shared__ ST items[TILE];
  __shared__ unsigned short dig[MODE == 1 ? TILE : 64];
  __shared__ unsigned short cnt[WAVES][RADIXN];
  __shared__ int exf[RADIXN];
  int s = blockIdx.y, b = blockIdx.x, tid = threadIdx.x;
  int wave = tid >> 6, lane = tid & 63;
  for (int j = tid; j < WAVES * RADIXN; j += BLOCK) ((unsigned short*)cnt)[j] = 0;
  __syncthreads();

  const KT* in = (const KT*)srcv + (size_t)s * N;
  int subbase = b * TILE + wave * SUBT;
  bool full = (subbase + SUBT <= N);
  KT k[CHUNKS]; u32 pd[CHUNKS];
  if (full) {
    #pragma unroll
    for (int t = 0; t < CHUNKS; t++) k[t] = in[subbase + t * 64 + lane];
    #pragma unroll
    for (int t = 0; t < CHUNKS; t++) {
      unsigned d = (unsigned)(k[t] >> SHIFT) & (RADIXN - 1);
      u64 m = ~0ull;
      #pragma unroll
      for (int bit = 0; bit < RB; bit++) {
        u64 bal = __ballot((d >> bit) & 1);
        m &= ((d >> bit) & 1) ? bal : ~bal;
      }
      unsigned rank = __builtin_amdgcn_mbcnt_hi((u32)(m >> 32),
                        __builtin_amdgcn_mbcnt_lo((u32)m, 0u));
      unsigned pbase = cnt[wave][d];              // lockstep: all read before leader writes
      pd[t] = d | ((pbase + rank) << RB);
      if (rank == 0) cnt[wave][d] = (unsigned short)(pbase + (unsigned)__popcll(m));
    }
  } else {
    #pragma unroll
    for (int t = 0; t < CHUNKS; t++) k[t] = in[min(subbase + t * 64 + lane, N - 1)];
    #pragma unroll
    for (int t = 0; t < CHUNKS; t++) {
      int i = subbase + t * 64 + lane;
      bool valid = i < N;
      unsigned d = (unsigned)(k[t] >> SHIFT) & (RADIXN - 1);
      u64 m = __ballot(valid);
      #pragma unroll
      for (int bit = 0; bit < RB; bit++) {
        u64 bal = __ballot(valid && ((d >> bit) & 1));
        m &= ((d >> bit) & 1) ? bal : ~bal;
      }
      unsigned rank = __builtin_amdgcn_mbcnt_hi((u32)(m >> 32),
                        __builtin_amdgcn_mbcnt_lo((u32)m, 0u));
      unsigned pbase = cnt[wave][d];
      pd[t] = d | ((pbase + rank) << RB);
      if (valid && rank == 0) cnt[wave][d] = (unsigned short)(pbase + (unsigned)__popcll(m));
    }
  }
  __syncthreads();

  // totals -> exf; stash per-wave counts in registers
  u32 sc[DPT][3];
  #pragma unroll
  for (int q = 0; q < DPT; q++) {
    int d = q * BLOCK + tid;
    u32 a0 = cnt[0][d], a1 = cnt[1][d], a2 = cnt[2][d], a3 = cnt[3][d];
    sc[q][0] = a0; sc[q][1] = a1; sc[q][2] = a2;
    exf[d] = (int)(a0 + a1 + a2 + a3);
  }
  __syncthreads();
  if (tid < 64) {                                 // wave0: exclusive scan of block totals
    u32 run = 0;
    #pragma unroll
    for (int c = 0; c < (RADIXN + 63) / 64; c++) {
      int dd = c * 64 + tid;
      u32 v = (u32)exf[dd], x = v;
      for (int off = 1; off < 64; off <<= 1) { u32 u = __shfl_up(x, off); if (tid >= off) x += u; }
      exf[dd] = (int)(run + x - v);
      run += __shfl(x, 63);
    }
  }
  __syncthreads();
  const u32* hrow = hist + (size_t)(s * B + b) * RADIXN;
  const u32* brow = dbase + (size_t)s * 512;
  #pragma unroll
  for (int q = 0; q < DPT; q++) {
    int d = q * BLOCK + tid;
    int e = exf[d];
    u32 gb = hrow[d] + brow[d];
    cnt[0][d] = (unsigned short)e;
    cnt[1][d] = (unsigned short)(e + sc[q][0]);
    cnt[2][d] = (unsigned short)(e + sc[q][0] + sc[q][1]);
    cnt[3][d] = (unsigned short)(e + sc[q][0] + sc[q][1] + sc[q][2]);
    exf[d] = (int)gb - e;                         // global = exf[d] + local slot
  }
  __syncthreads();

  #pragma unroll
  for (int t = 0; t < CHUNKS; t++) {
    int i = subbase + t * 64 + lane;
    if (i < N) {
      unsigned d = pd[t] & (RADIXN - 1);
      unsigned lr = pd[t] >> RB;
      unsigned pos = (unsigned)cnt[wave][d] + lr;
      if constexpr (MODE == 1) {
        items[pos] = (u32)(((k[t] >> 46) << 21) | ((u32)k[t] & KMASK));
        dig[pos] = (unsigned short)d;
      } else {
        items[pos] = (ST)k[t];
      }
    }
  }
  __syncthreads();

  int validCount = N - b * TILE; if (validCount > TILE) validCount = TILE;
  long long obase = 0;
  if (MODE == 2) obase = meta[25] + (long long)N * (1 + g0 + s);
  u64* out64 = (u64*)dstv + (size_t)s * N;
  u32* out32 = (u32*)dstv + (size_t)s * N;
  #pragma unroll 4
  for (int t = 0; t < CHUNKS; t++) {
    int j = t * BLOCK + tid;
    if (j < validCount) {
      ST kk = items[j];
      if constexpr (MODE == 0) {
        unsigned d = (unsigned)(kk >> SHIFT) & (RADIXN - 1);
        out64[exf[d] + j] = kk;
      } else if constexpr (MODE == 1) {
        unsigned d = dig[j];
        out32[exf[d] + j] = kk;
      } else {
        unsigned d = (unsigned)(kk >> SHIFT) & (RADIXN - 1);
        dout[obase + exf[d] + j] = (int)(kk & KMASK);
      }
    }
  }
}

extern "C" void kernel_launch(void* const* d_in, const int* in_sizes, int n_in,
                              void* d_out, int out_size, void* d_ws, size_t ws_size,
                              hipStream_t stream) {
  const int* coords = (const int*)d_in[0];
  const int* bsz    = (const int*)d_in[1];
  int N = in_sizes[0] / 4;
  int* dout = (int*)d_out;
  char* ws = (char*)d_ws;
  int B = (N + TILE - 1) / TILE;

  auto align256 = [](size_t x) { return (x + 255) & ~(size_t)255; };

  int g = 1;
  size_t offHist = 512, offBase = 0, offA = 0, offB = 0;
  const int cands[4] = {6, 3, 2, 1};
  for (int ci = 0; ci < 4; ci++) {
    int cg = cands[ci];
    size_t oBs = offHist + (size_t)cg * B * 512 * 4;
    size_t oA = align256(oBs + (size_t)cg * 512 * 4);
    size_t oB = oA + (size_t)cg * N * 8;
    size_t need = oB + (size_t)cg * N * 8;
    if (need <= ws_size || cg == 1) {
      g = cg; offBase = oBs; offA = oA; offB = oB;
      if (need <= ws_size) break;
    }
  }

  unsigned*  counts = (unsigned*)ws;
  long long* meta   = (long long*)(ws + 64);
  u32*       hist   = (u32*)(ws + offHist);
  u32*       dbase  = (u32*)(ws + offBase);
  u64*       keysA  = (u64*)(ws + offA);
  u64*       keysB  = (u64*)(ws + offB);

  hipMemsetAsync(ws, 0, 512, stream);
  count_k<<<1024, 256, 0, stream>>>(coords, counts, N);
  prefix_k<<<1, 1, 0, stream>>>(counts, meta, bsz);
  flat2win_k<<<(N + 8 * GRP + 255) / 256, 256, 0, stream>>>(meta, dout);

  for (int g0 = 0; g0 < 6; g0 += g) {
    keygen_k<<<B, BLOCK, 0, stream>>>(coords, keysA, hist, meta, dout, N, B, g0, g, g0 == 0);
    // pass 1: u64 radix 256 @21, A -> B
    scan_k<256><<<g, BLOCK, 0, stream>>>(hist, dbase, B);
    scatter_k<8, 21, 0><<<dim3(B, g), BLOCK, 0, stream>>>(keysA, keysB, hist, dbase, N, B,
                                                          dout, meta, g0);
    // pass 2: u64 radix 256 @29, B -> A
    hist_k<u64, 256, 29><<<dim3(B, g), BLOCK, 0, stream>>>(keysB, hist, N, B);
    scan_k<256><<<g, BLOCK, 0, stream>>>(hist, dbase, B);
    scatter_k<8, 29, 0><<<dim3(B, g), BLOCK, 0, stream>>>(keysB, keysA, hist, dbase, N, B,
                                                          dout, meta, g0);
    // pass 3: u64 radix 512 @37, A -> B (u32 shrink)
    hist_k<u64, 512, 37><<<dim3(B, g), BLOCK, 0, stream>>>(keysA, hist, N, B);
    scan_k<512><<<g, BLOCK, 0, stream>>>(hist, dbase, B);
    scatter_k<9, 37, 1><<<dim3(B, g), BLOCK, 0, stream>>>(keysA, keysB, hist, dbase, N, B,
                                                          dout, meta, g0);
    // pass 4: u32 radix 256 @21, B(u32) -> dout
    hist_k<u32, 256, 21><<<dim3(B, g), BLOCK, 0, stream>>>((const u32*)keysB, hist, N, B);
    scan_k<256><<<g, BLOCK, 0, stream>>>(hist, dbase, B);
    scatter_k<8, 21, 2><<<dim3(B, g), BLOCK, 0, stream>>>(keysB, keysA, hist, dbase, N, B,
                                                          dout, meta, g0);
  }
}